// Round 3
// baseline (39124.701 us; speedup 1.0000x reference)
//
#include <hip/hip_runtime.h>

typedef _Float16 f16;
typedef _Float16 f16x8 __attribute__((ext_vector_type(8)));
typedef float f32x4 __attribute__((ext_vector_type(4)));

#define NSTEPS 512
#define NBATCH 256
#define HID 256
#define PITCH 264          // f16 row pitch for 16-row h tiles
#define XPITCH 40          // layer-0 x tile pitch (32 cols used, 12 nonzero)
#define THREADS 1024
#define NWG 16
#define PFD 3              // B-prefetch depth in K-blocks (12 loads in flight/wave)

#define WPACK_OFF ((size_t)1024)
#define WPACK_ELEMS ((size_t)64*16*64*8)        // f16 elems per layer
#define WPACK_SZB (WPACK_ELEMS*2)               // 1 MiB per layer
#define WS_NEEDED (WPACK_OFF + 3*WPACK_SZB)

__device__ __forceinline__ float sigm(float x){ return 1.f/(1.f+__expf(-x)); }
__device__ __forceinline__ float tanh_f(float x){ return 1.f - 2.f/(1.f+__expf(2.f*x)); }

// weight packing: [layer][nt(64)][kb(16)][lane(64)][e(8)] f16
// B-fragment for mfma_f32_16x16x32_f16: col n = nt*16 + (lane&15), k = kb*32 + (lane>>4)*8 + e.
// k<256 -> w_hh[n][k]; k>=256 -> w_ih[n][k-256] (0-padded past in_dim).
__global__ __launch_bounds__(256) void pack_weights(
    const float* __restrict__ wih0, const float* __restrict__ whh0,
    const float* __restrict__ wih1, const float* __restrict__ whh1,
    const float* __restrict__ wih2, const float* __restrict__ whh2,
    unsigned char* __restrict__ ws)
{
  int gid = blockIdx.x*256 + threadIdx.x;
  if (gid >= 3*64*16*64) return;
  int lane  = gid & 63;
  int kb    = (gid>>6) & 15;
  int nt    = (gid>>10) & 15;
  nt += ((gid>>14) & 3) * 16;
  int layer = gid>>16;
  // recompute nt cleanly
  nt = (gid>>10) & 63;
  const float* whh = (layer==0)?whh0:((layer==1)?whh1:whh2);
  const float* wih = (layer==0)?wih0:((layer==1)?wih1:wih2);
  int indim = (layer==0)?12:256;
  int n  = nt*16 + (lane&15);
  int k0 = kb*32 + (lane>>4)*8;
  f16x8 v;
  #pragma unroll
  for (int e=0;e<8;++e){
    int k = k0+e;
    float x;
    if (k < HID) x = whh[n*HID + k];
    else { int ki = k-HID; x = (ki<indim)? wih[n*indim+ki] : 0.f; }
    v[e] = (f16)x;
  }
  f16* dst = (f16*)(ws + WPACK_OFF) + (size_t)layer*WPACK_ELEMS
           + ((size_t)(nt*16+kb)*64 + lane)*8;
  *(f16x8*)dst = v;
}

// Gates GEMM with register-staged B prefetch (depth PFD K-blocks).
// Wave w owns column-tile w for all four gates (nt = G*16 + w).
template<int KB>
__device__ __forceinline__ void gates_mfma(
    const f16* __restrict__ hl,   // own h_{t-1}, pitch PITCH (K lower half)
    const f16* __restrict__ up,   // x_t / h^{l-1}_t (K upper half)
    int upPitch,
    const f16* __restrict__ wp,   // packed weights, this layer
    const float* __restrict__ bias,
    int w, int lane, int c16,
    f32x4* __restrict__ acc)
{
  #pragma unroll
  for (int G=0;G<4;++G){
    f32x4 z = {bias[G],bias[G],bias[G],bias[G]};
    acc[G] = z;
  }
  f16x8 b[PFD][4];
  #pragma unroll
  for (int d=0; d<PFD; ++d)
    #pragma unroll
    for (int G=0; G<4; ++G)
      b[d][G] = *(const f16x8*)(wp + (((size_t)(G*16+w)*16 + d)<<9) + lane*8);
  #pragma unroll
  for (int kb=0; kb<KB; ++kb){
    const f16* ap = (kb<8) ? &hl[c16*PITCH + kb*32 + (lane>>4)*8]
                           : &up[c16*upPitch + (kb-8)*32 + (lane>>4)*8];
    f16x8 a = *(const f16x8*)ap;
    #pragma unroll
    for (int G=0; G<4; ++G)
      acc[G] = __builtin_amdgcn_mfma_f32_16x16x32_f16(a, b[kb%PFD][G], acc[G], 0,0,0);
    if (kb+PFD < KB){
      #pragma unroll
      for (int G=0; G<4; ++G)
        b[kb%PFD][G] = *(const f16x8*)(wp + (((size_t)(G*16+w)*16 + kb+PFD)<<9) + lane*8);
    }
  }
}

// 16 WGs x 1024 threads. WG = 16 batch rows, all 3 layers + linear head fused.
// No inter-WG communication. h single-buffered per layer (barrier between
// K-loop reads and cell writes).
__global__ __launch_bounds__(THREADS, 4) void lstm_fused(
    const float* __restrict__ input,
    const float* __restrict__ bih0, const float* __restrict__ bhh0,
    const float* __restrict__ bih1, const float* __restrict__ bhh1,
    const float* __restrict__ bih2, const float* __restrict__ bhh2,
    const float* __restrict__ wlin, const float* __restrict__ blin,
    const unsigned char* __restrict__ ws, float* __restrict__ out)
{
  __shared__ __attribute__((aligned(16))) f16 H[3][16*PITCH];
  __shared__ __attribute__((aligned(16))) f16 Ax0[16*XPITCH];
  __shared__ float Lout[16][16];

  const int tid  = threadIdx.x;
  const int w    = tid >> 6;          // 16 waves
  const int lane = tid & 63;
  const int c16  = lane & 15;
  const int r0   = (lane >> 4) * 4;
  const int rowsBase = blockIdx.x * 16;
  const int xr = tid/12, xc = tid - (tid/12)*12;
  const bool xth = (tid < 192);

  const f16* wp0 = (const f16*)(ws + WPACK_OFF);
  const f16* wp1 = wp0 + WPACK_ELEMS;
  const f16* wp2 = wp0 + 2*WPACK_ELEMS;

  const float* BIH[3] = {bih0,bih1,bih2};
  const float* BHH[3] = {bhh0,bhh1,bhh2};
  float bias[3][4], cst[3][4];
  #pragma unroll
  for (int l=0;l<3;++l)
    #pragma unroll
    for (int G=0;G<4;++G){
      int n = G*256 + w*16 + c16;
      bias[l][G] = BIH[l][n] + BHH[l][n];
      cst[l][G]  = 0.f;   // storage reused as [layer][q]
    }
  const float wl = wlin[w*16 + c16];
  const float bl = blin[0];

  for (int i=tid; i<3*16*PITCH; i+=THREADS) ((f16*)H)[i] = (f16)0.f;
  for (int i=tid; i<16*XPITCH;  i+=THREADS) Ax0[i] = (f16)0.f;
  __syncthreads();
  if (xth) Ax0[xr*XPITCH + xc] = (f16)input[((size_t)0*NBATCH + rowsBase + xr)*12 + xc];
  __syncthreads();

  f32x4 acc[4];

  for (int t=0; t<NSTEPS; ++t){
    // emit out(t-1) (Lout stable since prev step's last barrier)
    if (t > 0 && tid < 16){
      float s = bl;
      #pragma unroll
      for (int k=0;k<16;++k) s += Lout[tid][k];
      out[(size_t)(t-1)*NBATCH + rowsBase + tid] = s;
    }
    // preload next step's x into a register (consumed in phase 2)
    float xnext = 0.f;
    if (xth && t+1 < NSTEPS)
      xnext = input[((size_t)(t+1)*NBATCH + rowsBase + xr)*12 + xc];

    // ---- phase 0: layer 0 (x upper half is 1 K-block) ----
    gates_mfma<9>(H[0], Ax0, XPITCH, wp0, bias[0], w, lane, c16, acc);
    __syncthreads();   // reads of H[0] done
    #pragma unroll
    for (int q=0;q<4;++q){
      float gi = sigm  (acc[0][q]);
      float gf = sigm  (acc[1][q]);
      float gg = tanh_f(acc[2][q]);
      float go = sigm  (acc[3][q]);
      float cv = gf*cst[0][q] + gi*gg; cst[0][q]=cv;
      H[0][(r0+q)*PITCH + w*16 + c16] = (f16)(go*tanh_f(cv));
    }
    __syncthreads();   // H[0] now h^0_t

    // ---- phase 1: layer 1 ----
    gates_mfma<16>(H[1], H[0], PITCH, wp1, bias[1], w, lane, c16, acc);
    __syncthreads();
    #pragma unroll
    for (int q=0;q<4;++q){
      float gi = sigm  (acc[0][q]);
      float gf = sigm  (acc[1][q]);
      float gg = tanh_f(acc[2][q]);
      float go = sigm  (acc[3][q]);
      float cv = gf*cst[1][q] + gi*gg; cst[1][q]=cv;
      H[1][(r0+q)*PITCH + w*16 + c16] = (f16)(go*tanh_f(cv));
    }
    __syncthreads();

    // ---- phase 2: layer 2 + fused linear head ----
    gates_mfma<16>(H[2], H[1], PITCH, wp2, bias[2], w, lane, c16, acc);
    __syncthreads();
    float lp[4];
    #pragma unroll
    for (int q=0;q<4;++q){
      float gi = sigm  (acc[0][q]);
      float gf = sigm  (acc[1][q]);
      float gg = tanh_f(acc[2][q]);
      float go = sigm  (acc[3][q]);
      float cv = gf*cst[2][q] + gi*gg; cst[2][q]=cv;
      float h  = go*tanh_f(cv);
      H[2][(r0+q)*PITCH + w*16 + c16] = (f16)h;
      lp[q] = h*wl;
    }
    #pragma unroll
    for (int q=0;q<4;++q){
      #pragma unroll
      for (int off=1; off<16; off<<=1) lp[q] += __shfl_xor(lp[q], off);
    }
    if (c16==0){
      #pragma unroll
      for (int q=0;q<4;++q) Lout[r0+q][w] = lp[q];
    }
    if (xth) Ax0[xr*XPITCH + xc] = (f16)xnext;   // x_{t+1} (read next step ph0)
    __syncthreads();
  }

  if (tid < 16){
    float s = bl;
    #pragma unroll
    for (int k=0;k<16;++k) s += Lout[tid][k];
    out[(size_t)(NSTEPS-1)*NBATCH + rowsBase + tid] = s;
  }
}

extern "C" void kernel_launch(void* const* d_in, const int* in_sizes, int n_in,
                              void* d_out, int out_size, void* d_ws, size_t ws_size,
                              hipStream_t stream)
{
  const float* input=(const float*)d_in[0];
  const float* wih0 =(const float*)d_in[1];
  const float* whh0 =(const float*)d_in[2];
  const float* bih0 =(const float*)d_in[3];
  const float* bhh0 =(const float*)d_in[4];
  const float* wih1 =(const float*)d_in[5];
  const float* whh1 =(const float*)d_in[6];
  const float* bih1 =(const float*)d_in[7];
  const float* bhh1 =(const float*)d_in[8];
  const float* wih2 =(const float*)d_in[9];
  const float* whh2 =(const float*)d_in[10];
  const float* bih2 =(const float*)d_in[11];
  const float* bhh2 =(const float*)d_in[12];
  const float* wlin =(const float*)d_in[13];
  const float* blin =(const float*)d_in[14];
  unsigned char* ws = (unsigned char*)d_ws;
  if (ws_size < WS_NEEDED) return;   // ~3.1 MB needed

  hipLaunchKernelGGL(pack_weights, dim3(768), dim3(256), 0, stream,
                     wih0,whh0,wih1,whh1,wih2,whh2, ws);
  hipLaunchKernelGGL(lstm_fused, dim3(NWG), dim3(THREADS), 0, stream,
                     input, bih0,bhh0,bih1,bhh1,bih2,bhh2, wlin, blin,
                     ws, (float*)d_out);
}

// Round 4
// 35164.853 us; speedup vs baseline: 1.1126x; 1.1126x over previous
//
#include <hip/hip_runtime.h>

typedef _Float16 f16;
typedef _Float16 f16x8 __attribute__((ext_vector_type(8)));
typedef float f32x4 __attribute__((ext_vector_type(4)));

#define NSTEPS 512
#define NBATCH 256
#define HID 256
#define PITCH 264          // f16 row pitch for 16-row h tiles
#define XPITCH 40          // layer-0 x tile pitch
#define THREADS 1024
#define NWG 16

#define WPACK_OFF ((size_t)1024)
#define WPACK_ELEMS ((size_t)64*16*64*8)        // f16 elems per layer
#define WPACK_SZB (WPACK_ELEMS*2)               // 1 MiB per layer
#define WS_NEEDED (WPACK_OFF + 3*WPACK_SZB)

__device__ __forceinline__ float sigm(float x){ return 1.f/(1.f+__expf(-x)); }
__device__ __forceinline__ float tanh_f(float x){ return 1.f - 2.f/(1.f+__expf(2.f*x)); }

// weight packing: [layer][nt(64)][kb(16)][lane(64)][e(8)] f16
// Each (nt,kb) fragment is a contiguous 1KB chunk, lane l owns bytes [16l,16l+16)
// -> exactly the global_load_lds width-16 source layout.
__global__ __launch_bounds__(256) void pack_weights(
    const float* __restrict__ wih0, const float* __restrict__ whh0,
    const float* __restrict__ wih1, const float* __restrict__ whh1,
    const float* __restrict__ wih2, const float* __restrict__ whh2,
    unsigned char* __restrict__ ws)
{
  int gid = blockIdx.x*256 + threadIdx.x;
  if (gid >= 3*64*16*64) return;
  int lane  = gid & 63;
  int kb    = (gid>>6) & 15;
  int nt    = (gid>>10) & 63;
  int layer = gid>>16;
  const float* whh = (layer==0)?whh0:((layer==1)?whh1:whh2);
  const float* wih = (layer==0)?wih0:((layer==1)?wih1:wih2);
  int indim = (layer==0)?12:256;
  int n  = nt*16 + (lane&15);
  int k0 = kb*32 + (lane>>4)*8;
  f16x8 v;
  #pragma unroll
  for (int e=0;e<8;++e){
    int k = k0+e;
    float x;
    if (k < HID) x = whh[n*HID + k];
    else { int ki = k-HID; x = (ki<indim)? wih[n*indim+ki] : 0.f; }
    v[e] = (f16)x;
  }
  f16* dst = (f16*)(ws + WPACK_OFF) + (size_t)layer*WPACK_ELEMS
           + ((size_t)(nt*16+kb)*64 + lane)*8;
  *(f16x8*)dst = v;
}

// Gates GEMM with wave-private double-buffered global_load_lds B-pipeline.
// Wave w owns column-tile w for all four gates (nt = G*16 + w); it stages its
// own B-fragments, so the pipeline needs NO cross-wave barriers.
template<int KB>
__device__ __forceinline__ void gates_mfma(
    const f16* __restrict__ hl,   // h_{t-1}, pitch PITCH (K lower half, 8 kb)
    const f16* __restrict__ up,   // x_t / h^{l-1}_t (K upper half)
    int upPitch,
    const f16* __restrict__ wp,   // packed weights (GLOBAL), this layer
    f16* __restrict__ bst,        // this wave's LDS stage: [2][4][512] f16 = 8KB
    const float* __restrict__ bias,
    int w, int lane, int c16,
    f32x4* __restrict__ acc)
{
  // exact vmcnt accounting: drain any prior global ops (x-load / out-store)
  asm volatile("s_waitcnt vmcnt(0)" ::: "memory");
  const char* gbase = (const char*)wp + ((size_t)w*16*1024) + (size_t)lane*16;
  // frag (G,kb) at byte offset G*262144 + kb*1024 from gbase
  #pragma unroll
  for (int G=0; G<4; ++G)
    __builtin_amdgcn_global_load_lds(
      (const __attribute__((address_space(1))) unsigned int*)(gbase + (size_t)G*262144),
      (__attribute__((address_space(3))) unsigned int*)(bst + G*512),
      16, 0, 0);
  #pragma unroll
  for (int G=0;G<4;++G){ f32x4 z={bias[G],bias[G],bias[G],bias[G]}; acc[G]=z; }

  #pragma unroll
  for (int kb=0; kb<KB; ++kb){
    const int par = kb & 1, nxt = par ^ 1;
    if (kb+1 < KB){
      #pragma unroll
      for (int G=0; G<4; ++G)
        __builtin_amdgcn_global_load_lds(
          (const __attribute__((address_space(1))) unsigned int*)
              (gbase + (size_t)G*262144 + (size_t)(kb+1)*1024),
          (__attribute__((address_space(3))) unsigned int*)(bst + nxt*2048 + G*512),
          16, 0, 0);
      asm volatile("s_waitcnt vmcnt(4)" ::: "memory");   // kb's 4 frags landed
    } else {
      asm volatile("s_waitcnt vmcnt(0)" ::: "memory");
    }
    __builtin_amdgcn_sched_barrier(0);   // pin: no LDS reads above the wait
    const f16* ap = (kb<8) ? &hl[c16*PITCH + kb*32 + (lane>>4)*8]
                           : &up[c16*upPitch + (kb-8)*32 + (lane>>4)*8];
    f16x8 a = *(const f16x8*)ap;
    #pragma unroll
    for (int G=0; G<4; ++G){
      f16x8 b = *(const f16x8*)(bst + par*2048 + G*512 + lane*8);
      acc[G] = __builtin_amdgcn_mfma_f32_16x16x32_f16(a, b, acc[G], 0,0,0);
    }
  }
}

// 16 WGs x 1024 threads. WG = 16 batch rows, 3 layers + head fused, zero inter-WG sync.
__global__ __launch_bounds__(THREADS, 4) void lstm_fused(
    const float* __restrict__ input,
    const float* __restrict__ bih0, const float* __restrict__ bhh0,
    const float* __restrict__ bih1, const float* __restrict__ bhh1,
    const float* __restrict__ bih2, const float* __restrict__ bhh2,
    const float* __restrict__ wlin, const float* __restrict__ blin,
    const unsigned char* __restrict__ ws, float* __restrict__ out)
{
  __shared__ __attribute__((aligned(16))) f16 Bst[16][2][4][512];  // 128KB, wave-private slots
  __shared__ __attribute__((aligned(16))) f16 H[3][16*PITCH];      // 25KB
  __shared__ __attribute__((aligned(16))) f16 Ax0[16*XPITCH];
  __shared__ float Lout[16][16];

  const int tid  = threadIdx.x;
  const int w    = tid >> 6;          // 16 waves
  const int lane = tid & 63;
  const int c16  = lane & 15;
  const int r0   = (lane >> 4) * 4;
  const int rowsBase = blockIdx.x * 16;
  const int xr = tid/12, xc = tid - (tid/12)*12;
  const bool xth = (tid < 192);

  const f16* wp0 = (const f16*)(ws + WPACK_OFF);
  const f16* wp1 = wp0 + WPACK_ELEMS;
  const f16* wp2 = wp0 + 2*WPACK_ELEMS;
  f16* bst = &Bst[w][0][0][0];

  const float* BIH[3] = {bih0,bih1,bih2};
  const float* BHH[3] = {bhh0,bhh1,bhh2};
  float bias[3][4], cst[3][4];
  #pragma unroll
  for (int l=0;l<3;++l)
    #pragma unroll
    for (int G=0;G<4;++G){
      int n = G*256 + w*16 + c16;
      bias[l][G] = BIH[l][n] + BHH[l][n];
      cst[l][G]  = 0.f;   // storage reused as [layer][q]
    }
  const float wl = wlin[w*16 + c16];
  const float bl = blin[0];

  for (int i=tid; i<3*16*PITCH; i+=THREADS) ((f16*)H)[i] = (f16)0.f;
  for (int i=tid; i<16*XPITCH;  i+=THREADS) Ax0[i] = (f16)0.f;
  __syncthreads();
  if (xth) Ax0[xr*XPITCH + xc] = (f16)input[((size_t)0*NBATCH + rowsBase + xr)*12 + xc];
  __syncthreads();

  f32x4 acc[4];

  for (int t=0; t<NSTEPS; ++t){
    // ---- phase 0: layer 0 ----
    gates_mfma<9>(H[0], Ax0, XPITCH, wp0, bst, bias[0], w, lane, c16, acc);
    __syncthreads();
    #pragma unroll
    for (int q=0;q<4;++q){
      float gi = sigm  (acc[0][q]);
      float gf = sigm  (acc[1][q]);
      float gg = tanh_f(acc[2][q]);
      float go = sigm  (acc[3][q]);
      float cv = gf*cst[0][q] + gi*gg; cst[0][q]=cv;
      H[0][(r0+q)*PITCH + w*16 + c16] = (f16)(go*tanh_f(cv));
    }
    // out(t-1) store + x(t+1) stage live here (drained at next gates entry)
    if (t > 0 && tid < 16){
      float s = bl;
      #pragma unroll
      for (int k=0;k<16;++k) s += Lout[tid][k];
      out[(size_t)(t-1)*NBATCH + rowsBase + tid] = s;
    }
    if (xth && t+1 < NSTEPS)
      Ax0[xr*XPITCH + xc] = (f16)input[((size_t)(t+1)*NBATCH + rowsBase + xr)*12 + xc];
    __syncthreads();

    // ---- phase 1: layer 1 ----
    gates_mfma<16>(H[1], H[0], PITCH, wp1, bst, bias[1], w, lane, c16, acc);
    __syncthreads();
    #pragma unroll
    for (int q=0;q<4;++q){
      float gi = sigm  (acc[0][q]);
      float gf = sigm  (acc[1][q]);
      float gg = tanh_f(acc[2][q]);
      float go = sigm  (acc[3][q]);
      float cv = gf*cst[1][q] + gi*gg; cst[1][q]=cv;
      H[1][(r0+q)*PITCH + w*16 + c16] = (f16)(go*tanh_f(cv));
    }
    __syncthreads();

    // ---- phase 2: layer 2 + fused linear head ----
    gates_mfma<16>(H[2], H[1], PITCH, wp2, bst, bias[2], w, lane, c16, acc);
    __syncthreads();
    float lp[4];
    #pragma unroll
    for (int q=0;q<4;++q){
      float gi = sigm  (acc[0][q]);
      float gf = sigm  (acc[1][q]);
      float gg = tanh_f(acc[2][q]);
      float go = sigm  (acc[3][q]);
      float cv = gf*cst[2][q] + gi*gg; cst[2][q]=cv;
      float h  = go*tanh_f(cv);
      H[2][(r0+q)*PITCH + w*16 + c16] = (f16)h;
      lp[q] = h*wl;
    }
    #pragma unroll
    for (int q=0;q<4;++q){
      #pragma unroll
      for (int off=1; off<16; off<<=1) lp[q] += __shfl_xor(lp[q], off);
    }
    if (c16==0){
      #pragma unroll
      for (int q=0;q<4;++q) Lout[r0+q][w] = lp[q];
    }
    __syncthreads();
  }

  if (tid < 16){
    float s = bl;
    #pragma unroll
    for (int k=0;k<16;++k) s += Lout[tid][k];
    out[(size_t)(NSTEPS-1)*NBATCH + rowsBase + tid] = s;
  }
}

extern "C" void kernel_launch(void* const* d_in, const int* in_sizes, int n_in,
                              void* d_out, int out_size, void* d_ws, size_t ws_size,
                              hipStream_t stream)
{
  const float* input=(const float*)d_in[0];
  const float* wih0 =(const float*)d_in[1];
  const float* whh0 =(const float*)d_in[2];
  const float* bih0 =(const float*)d_in[3];
  const float* bhh0 =(const float*)d_in[4];
  const float* wih1 =(const float*)d_in[5];
  const float* whh1 =(const float*)d_in[6];
  const float* bih1 =(const float*)d_in[7];
  const float* bhh1 =(const float*)d_in[8];
  const float* wih2 =(const float*)d_in[9];
  const float* whh2 =(const float*)d_in[10];
  const float* bih2 =(const float*)d_in[11];
  const float* bhh2 =(const float*)d_in[12];
  const float* wlin =(const float*)d_in[13];
  const float* blin =(const float*)d_in[14];
  unsigned char* ws = (unsigned char*)d_ws;
  if (ws_size < WS_NEEDED) return;   // ~3.1 MB needed

  hipLaunchKernelGGL(pack_weights, dim3(768), dim3(256), 0, stream,
                     wih0,whh0,wih1,whh1,wih2,whh2, ws);
  hipLaunchKernelGGL(lstm_fused, dim3(NWG), dim3(THREADS), 0, stream,
                     input, bih0,bhh0,bih1,bhh1,bih2,bhh2, wlin, blin,
                     ws, (float*)d_out);
}

// Round 6
// 10412.955 us; speedup vs baseline: 3.7573x; 3.3770x over previous
//
#include <hip/hip_runtime.h>

typedef _Float16 f16;
typedef _Float16 f16x8 __attribute__((ext_vector_type(8)));
typedef float f32x4 __attribute__((ext_vector_type(4)));

#define NSTEPS 512
#define NBATCH 256
#define HID 256
#define NL 3
#define NBG 8              // batch groups of 32 rows
#define NNW 8              // N-split: 32 hidden units per WG
#define ROWS 32
#define DRING 8            // ring depth (steps)
#define PITCH 264          // f16 row pitch (528B: 2-way LDS aliasing only)
#define THREADS 256
#define BKB 15             // K-blocks of B kept in LDS (kb 15 in VGPRs)

#define WPACK_OFF ((size_t)1024)
#define WPACK_ELEMS ((size_t)64*16*64*8)        // f16 per layer
#define WPACK_SZB (WPACK_ELEMS*2)               // 1 MiB per layer
#define RING_OFF (WPACK_OFF + 3*WPACK_SZB)
#define SLOT_F16 ((size_t)ROWS*HID)             // 8192 f16 = 16KB
#define RING_SZB ((size_t)NL*NBG*DRING*SLOT_F16*2)
#define WS_NEEDED (RING_OFF + RING_SZB)

__device__ __forceinline__ float sigm(float x){ return 1.f/(1.f+__expf(-x)); }
__device__ __forceinline__ float tanh_f(float x){ return 1.f - 2.f/(1.f+__expf(2.f*x)); }

// packed weights: [layer][nt(64)][kb(16)][lane(64)][e(8)] f16
// B-frag (mfma_f32_16x16x32_f16): col n = nt*16+(lane&15), k = kb*32+(lane>>4)*8+e.
// k<256 -> w_hh[n][k]; k>=256 -> w_ih[n][k-256] (0-padded past in_dim).
__global__ __launch_bounds__(256) void pack_weights(
    const float* __restrict__ wih0, const float* __restrict__ whh0,
    const float* __restrict__ wih1, const float* __restrict__ whh1,
    const float* __restrict__ wih2, const float* __restrict__ whh2,
    unsigned char* __restrict__ ws)
{
  int gid = blockIdx.x*256 + threadIdx.x;
  if (gid >= 3*64*16*64) return;
  int lane  = gid & 63;
  int kb    = (gid>>6) & 15;
  int nt    = (gid>>10) & 63;
  int layer = gid>>16;
  const float* whh = (layer==0)?whh0:((layer==1)?whh1:whh2);
  const float* wih = (layer==0)?wih0:((layer==1)?wih1:wih2);
  int indim = (layer==0)?12:256;
  int n  = nt*16 + (lane&15);
  int k0 = kb*32 + (lane>>4)*8;
  f16x8 v;
  #pragma unroll
  for (int e=0;e<8;++e){
    int k = k0+e;
    float x;
    if (k < HID) x = whh[n*HID + k];
    else { int ki = k-HID; x = (ki<indim)? wih[n*indim+ki] : 0.f; }
    v[e] = (f16)x;
  }
  f16* dst = (f16*)(ws + WPACK_OFF) + (size_t)layer*WPACK_ELEMS
           + ((size_t)(nt*16+kb)*64 + lane)*8;
  *(f16x8*)dst = v;
}

// 3-role poll in one ballot. role0: own>=tOwn, role1: low>=tLow, role2: up>=tUp.
__device__ __forceinline__ void poll3(int* fOwn, int tOwn,
                                      int* fLow, int tLow,
                                      int* fUp,  int tUp, int lane)
{
  const int role = lane>>3, idx = lane&7;
  int* p; int need;
  if      (role==0){ p=fOwn; need=tOwn; }
  else if (role==1){ p=fLow; need=tLow; }
  else if (role==2){ p=fUp;  need=tUp;  }
  else             { p=fOwn; need=-2000000000; }
  int guard = 0;
  for(;;){
    int v = __hip_atomic_load(p+idx, __ATOMIC_RELAXED, __HIP_MEMORY_SCOPE_AGENT);
    if (__all(v >= need)) break;
    if (++guard > (1<<22)) break;               // bounded: fail visibly, never hang
    __builtin_amdgcn_s_sleep(1);
  }
}

template<int KB>
__device__ __forceinline__ void gates_mfma(
    const f16* __restrict__ Hown, const f16* __restrict__ Hin,
    const f16* __restrict__ BstL,      // LDS-packed B, this WG (8 nt x BKB kb)
    const f16x8* __restrict__ b15,     // [4] kb=15 frags in regs
    int wm, int wn, int lane, int c16, f32x4* acc)
{
  const int arow = wm*16 + c16;
  #pragma unroll
  for (int kb=0; kb<KB; ++kb){
    const f16* ap = (kb<8) ? &Hown[arow*PITCH + kb*32 + (lane>>4)*8]
                           : &Hin [arow*PITCH + (kb-8)*32 + (lane>>4)*8];
    f16x8 a = *(const f16x8*)ap;
    #pragma unroll
    for (int G=0; G<4; ++G){
      f16x8 b;
      if (kb < BKB)
        b = ((const f16x8*)BstL)[ (size_t)((G*2+wn)*BKB + kb)*64 + lane ];
      else
        b = b15[G];
      acc[G] = __builtin_amdgcn_mfma_f32_16x16x32_f16(a, b, acc[G], 0,0,0);
    }
  }
}

// 192 WGs = 3 layers x 8 batch-groups x 8 N-groups. Weights LDS-stationary.
// bid = ((layer*8 + nw)<<3) | bg  -> all 24 WGs of a batch-group share an XCD.
__global__ __launch_bounds__(THREADS) void lstm_ws(
    const float* __restrict__ input,
    const float* __restrict__ bih0, const float* __restrict__ bhh0,
    const float* __restrict__ bih1, const float* __restrict__ bhh1,
    const float* __restrict__ bih2, const float* __restrict__ bhh2,
    const float* __restrict__ wlin, const float* __restrict__ blin,
    unsigned char* __restrict__ ws, float* __restrict__ out)
{
  __shared__ __attribute__((aligned(16))) f16 Bst[8*BKB*64*8];   // 122880 B
  __shared__ __attribute__((aligned(16))) f16 Hown[ROWS*PITCH];  // 16896 B
  __shared__ __attribute__((aligned(16))) f16 Hin [ROWS*PITCH];  // 16896 B
  __shared__ float wlinLDS[HID];                                 // 1024 B

  const int tid  = threadIdx.x;
  const int w    = tid >> 6;          // 4 waves
  const int wm   = w >> 1, wn = w & 1;
  const int lane = tid & 63;
  const int c16  = lane & 15;
  const int r0   = (lane >> 4) * 4;
  const int bid  = blockIdx.x;
  const int bg   = bid & 7;
  const int nw   = (bid >> 3) & 7;
  const int layer= bid >> 6;
  const int rowsBase = bg * ROWS;
  const int unitBase = nw * 32;

  int* flags = (int*)ws;                              // [24][8]
  int* fOwn  = flags + (layer*NBG + bg)*8;
  int* fLow  = (layer>0)? flags + ((layer-1)*NBG + bg)*8 : fOwn;
  int* fUp   = (layer<2)? flags + ((layer+1)*NBG + bg)*8 : fOwn;
  const int tLowDummy = -2000000000;

  const f16* wp = (const f16*)(ws + WPACK_OFF) + (size_t)layer*WPACK_ELEMS;
  f16* ringSelf = (f16*)(ws + RING_OFF) + (size_t)((layer*NBG + bg)*DRING)*SLOT_F16;
  f16* ringLow  = (layer>0)? (f16*)(ws + RING_OFF) + (size_t)(((layer-1)*NBG + bg)*DRING)*SLOT_F16 : (f16*)0;

  // ---- one-time: weights -> LDS (kb<15) and regs (kb 15) ----
  const f16x8* wpv = (const f16x8*)wp;                 // 16B units
  f16x8* Bv = (f16x8*)Bst;
  #pragma unroll
  for (int nl=0; nl<8; ++nl){
    int G = nl>>1, s = nl&1;
    int nt = G*16 + nw*2 + s;
    for (int idx=tid; idx<BKB*64; idx+=THREADS)
      Bv[(size_t)nl*BKB*64 + idx] = wpv[(size_t)nt*1024 + idx];
  }
  f16x8 b15[4];
  #pragma unroll
  for (int G=0; G<4; ++G){
    int nt = G*16 + nw*2 + wn;
    b15[G] = wpv[(size_t)nt*1024 + 15*64 + lane];
  }
  if (tid < HID) wlinLDS[tid] = wlin[tid];

  const float* BIH = (layer==0)?bih0:((layer==1)?bih1:bih2);
  const float* BHH = (layer==0)?bhh0:((layer==1)?bhh1:bhh2);
  float bias[4], cst[4];
  const int unit = unitBase + wn*16 + c16;
  #pragma unroll
  for (int G=0;G<4;++G){
    int n = G*HID + unit;
    bias[G] = BIH[n] + BHH[n];
    cst[G] = 0.f;                                   // reused as [q]
  }
  const float bl = blin[0];

  for (int i=tid; i<ROWS*PITCH; i+=THREADS){ Hown[i]=(f16)0.f; Hin[i]=(f16)0.f; }
  __syncthreads();

  for (int t=0; t<NSTEPS; ++t){
    // ---- wait: own peers >= t, lower >= t+1, upper >= t-DRING+1 ----
    poll3(fOwn, t,
          fLow, (layer>0)? t+1 : tLowDummy,
          fUp,  (layer<2)? t-DRING+1 : tLowDummy, lane);
    __builtin_amdgcn_fence(__ATOMIC_ACQUIRE, "agent");

    // ---- stage A tiles from rings ----
    if (t > 0){
      const f16x8* src = (const f16x8*)(ringSelf + (size_t)((t-1)&(DRING-1))*SLOT_F16);
      for (int i=tid; i<1024; i+=THREADS){
        int row = i>>5, c = i&31;
        ((f16x8*)Hown)[row*33 + c] = src[i];
      }
    }
    if (layer > 0){
      const f16x8* src = (const f16x8*)(ringLow + (size_t)(t&(DRING-1))*SLOT_F16);
      for (int i=tid; i<1024; i+=THREADS){
        int row = i>>5, c = i&31;
        ((f16x8*)Hin)[row*33 + c] = src[i];
      }
    } else {
      for (int idx=tid; idx<ROWS*12; idx+=THREADS){
        int r = idx/12, i = idx - r*12;
        Hin[r*PITCH + i] = (f16)input[((size_t)t*NBATCH + rowsBase + r)*12 + i];
      }
    }
    __syncthreads();

    // ---- fused linear head from h_{t-1} (layer 2; Hown holds h_{t-1}) ----
    if (layer==2 && t>0){
      int row = tid>>3, kc = tid&7;
      float s = 0.f;
      #pragma unroll
      for (int cc=0; cc<4; ++cc){
        f16x8 hv = *(const f16x8*)&Hown[row*PITCH + kc*32 + cc*8];
        #pragma unroll
        for (int j=0;j<8;++j) s += (float)hv[j] * wlinLDS[kc*32 + cc*8 + j];
      }
      s += __shfl_xor(s,1); s += __shfl_xor(s,2); s += __shfl_xor(s,4);
      if (kc==0) out[(size_t)(t-1)*NBATCH + rowsBase + row] = s + bl;
    }

    // ---- gates GEMM + cell ----
    f32x4 acc[4];
    #pragma unroll
    for (int G=0;G<4;++G){ f32x4 z={bias[G],bias[G],bias[G],bias[G]}; acc[G]=z; }
    if (layer==0) gates_mfma<9> (Hown, Hin, Bst, b15, wm, wn, lane, c16, acc);
    else          gates_mfma<16>(Hown, Hin, Bst, b15, wm, wn, lane, c16, acc);

    f16* slot = ringSelf + (size_t)(t&(DRING-1))*SLOT_F16;
    #pragma unroll
    for (int q=0;q<4;++q){
      float gi = sigm  (acc[0][q]);
      float gf = sigm  (acc[1][q]);
      float gg = tanh_f(acc[2][q]);
      float go = sigm  (acc[3][q]);
      float cv = gf*cst[q] + gi*gg; cst[q]=cv;
      float h  = go*tanh_f(cv);
      slot[(wm*16 + r0 + q)*HID + unit] = (f16)h;
    }
    __builtin_amdgcn_fence(__ATOMIC_RELEASE, "agent");   // order own ring stores
    __syncthreads();                                     // all waves done
    if (tid==0)
      __hip_atomic_store(fOwn + nw, t+1, __ATOMIC_RELEASE, __HIP_MEMORY_SCOPE_AGENT);
  }

  // ---- epilogue: out[511] from h_511 (layer 2) ----
  if (layer==2){
    poll3(fOwn, NSTEPS, fOwn, tLowDummy, fOwn, tLowDummy, lane);
    __builtin_amdgcn_fence(__ATOMIC_ACQUIRE, "agent");
    const f16x8* src = (const f16x8*)(ringSelf + (size_t)((NSTEPS-1)&(DRING-1))*SLOT_F16);
    for (int i=tid; i<1024; i+=THREADS){
      int row = i>>5, c = i&31;
      ((f16x8*)Hown)[row*33 + c] = src[i];
    }
    __syncthreads();
    int row = tid>>3, kc = tid&7;
    float s = 0.f;
    #pragma unroll
    for (int cc=0; cc<4; ++cc){
      f16x8 hv = *(const f16x8*)&Hown[row*PITCH + kc*32 + cc*8];
      #pragma unroll
      for (int j=0;j<8;++j) s += (float)hv[j] * wlinLDS[kc*32 + cc*8 + j];
    }
    s += __shfl_xor(s,1); s += __shfl_xor(s,2); s += __shfl_xor(s,4);
    if (kc==0) out[(size_t)(NSTEPS-1)*NBATCH + rowsBase + row] = s + bl;
  }
}

extern "C" void kernel_launch(void* const* d_in, const int* in_sizes, int n_in,
                              void* d_out, int out_size, void* d_ws, size_t ws_size,
                              hipStream_t stream)
{
  const float* input=(const float*)d_in[0];
  const float* wih0 =(const float*)d_in[1];
  const float* whh0 =(const float*)d_in[2];
  const float* bih0 =(const float*)d_in[3];
  const float* bhh0 =(const float*)d_in[4];
  const float* wih1 =(const float*)d_in[5];
  const float* whh1 =(const float*)d_in[6];
  const float* bih1 =(const float*)d_in[7];
  const float* bhh1 =(const float*)d_in[8];
  const float* wih2 =(const float*)d_in[9];
  const float* whh2 =(const float*)d_in[10];
  const float* bih2 =(const float*)d_in[11];
  const float* bhh2 =(const float*)d_in[12];
  const float* wlin =(const float*)d_in[13];
  const float* blin =(const float*)d_in[14];
  unsigned char* ws = (unsigned char*)d_ws;
  if (ws_size < WS_NEEDED) return;   // ~6.3 MB needed

  (void)hipMemsetAsync(ws, 0, 1024, stream);   // flags
  hipLaunchKernelGGL(pack_weights, dim3(768), dim3(256), 0, stream,
                     wih0,whh0,wih1,whh1,wih2,whh2, ws);
  hipLaunchKernelGGL(lstm_ws, dim3(NL*NBG*NNW), dim3(THREADS), 0, stream,
                     input, bih0,bhh0,bih1,bhh1,bih2,bhh2, wlin, blin,
                     ws, (float*)d_out);
}